// Round 2
// baseline (232.536 us; speedup 1.0000x reference)
//
#include <hip/hip_runtime.h>

// out[2i]   = x[2i]
// out[2i+1] = x[2i+1] - x[2i] / 50
// Pure elementwise on adjacent pairs -> memory-bound. float4 = two pairs per
// lane, 16B/lane coalesced.
//
// Round-1 lesson (kept): all indexing derives from out_size only (in_sizes[0]
// previously caused OOB writes that clobbered the harness's pristine copy).
//
// Round-2 lesson: __builtin_nontemporal_store requires a NATIVE vector type;
// HIP's float4 (HIP_vector_type wrapper class) is rejected. Use a clang
// ext_vector_type alias (identical 16B layout) for the store.
//
// This round:
//  - Grid-stride loop with grid capped at 2048 blocks (8 blocks/CU x 256 CUs),
//    amortizing dispatch ramp instead of 32768 one-shot blocks.
//  - Non-temporal stores for the output: it is write-once/never-re-read, so
//    keep it out of L2/L3 and leave LLC capacity to the input stream (input
//    is 128 MB, L3 is 256 MB -> input can stay resident across iterations).

typedef float f32x4 __attribute__((ext_vector_type(4)));

__global__ __launch_bounds__(256) void dn_kernel(const f32x4* __restrict__ in,
                                                 f32x4* __restrict__ out,
                                                 int n4) {
    const int stride = gridDim.x * blockDim.x;
    for (int i = blockIdx.x * blockDim.x + threadIdx.x; i < n4; i += stride) {
        f32x4 v = in[i];
        f32x4 r;
        r.x = v.x;
        r.y = v.y - v.x * (1.0f / 50.0f);
        r.z = v.z;
        r.w = v.w - v.z * (1.0f / 50.0f);
        __builtin_nontemporal_store(r, &out[i]);
    }
}

// Scalar tail in case out_size is not a multiple of 4 (not expected here,
// but keeps the kernel fully general without relying on in_sizes).
__global__ void dn_tail_kernel(const float* __restrict__ in,
                               float* __restrict__ out,
                               int start, int n) {
    int i = start + blockIdx.x * blockDim.x + threadIdx.x;
    if (i < n) {
        float v = in[i];
        if (i & 1) {
            out[i] = v - in[i - 1] * (1.0f / 50.0f);
        } else {
            out[i] = v;
        }
    }
}

extern "C" void kernel_launch(void* const* d_in, const int* in_sizes, int n_in,
                              void* d_out, int out_size, void* d_ws, size_t ws_size,
                              hipStream_t stream) {
    const float* in = (const float*)d_in[0];
    float* out = (float*)d_out;
    int n = out_size;             // 128*64*64*64 = 33,554,432 fp32 elements
    int n4 = n / 4;               // float4 count: 8,388,608
    if (n4 > 0) {
        int block = 256;
        int grid = (n4 + block - 1) / block;
        if (grid > 2048) grid = 2048;   // 8 blocks/CU * 256 CUs; grid-stride covers the rest
        dn_kernel<<<grid, block, 0, stream>>>((const f32x4*)in, (f32x4*)out, n4);
    }
    int tail_start = n4 * 4;
    int tail = n - tail_start;
    if (tail > 0) {
        dn_tail_kernel<<<1, 64, 0, stream>>>(in, out, tail_start, n);
    }
}